// Round 6
// baseline (33331.775 us; speedup 1.0000x reference)
//
#include <hip/hip_runtime.h>
#include <cstdint>
#include <cstddef>

#define TT 512
#define NWG 256
#define SCH 32            /* steps per chunk */
#define NCH 16            /* chunks */

// ---- Workspace layout (BYTE offsets). Total ~174 MB.
#define OFF_H0   0ul
#define SZ_H0    (512ul*1024ul*64ul*2ul)          /* layer0 out, bf16 (T,1024,B)  64MiB */
#define OFF_OUT  (OFF_H0 + SZ_H0)
#define SZ_OUT   (512ul*512ul*64ul*4ul)           /* layer1 fwd+bwd sum fp32 (T,512,B) 64MiB */
#define OFF_XW   (OFF_OUT + SZ_OUT)
#define SZ_XW    (2ul*(size_t)SCH*2048ul*64ul*4ul)/* xW chunk [d][sl][g][b] fp32 32MiB */
#define OFF_HBUF (OFF_XW + SZ_XW)
#define SZ_HBUF  (2ul*2ul*2ul*512ul*64ul*4ul)     /* [layer][pp][dir][j][b] fp32 */
#define OFF_CST  (OFF_HBUF + SZ_HBUF)
#define SZ_CST   (2ul*2ul*512ul*64ul*4ul)         /* cell state fp32 */
#define OFF_FLG  (OFF_CST + SZ_CST)
#define SZ_FLG   (2ul*2ul*512ul*128ul*4ul)        /* u32 flags [layer][dir][step][slot] */
#define OFF_E    (OFF_FLG + SZ_FLG)
#define SZ_E     (64ul*512ul*4ul)
#define OFF_AT   (OFF_E + SZ_E)
#define SZ_AT    (512ul*64ul*4ul)
#define OFF_POOL (OFF_AT + SZ_AT)
#define SZ_POOL  (512ul*64ul*4ul)

#define RECUR_LDS_BYTES 49152   /* wlds 16x512 fp32 (32KB) + red scratch 16KB */

__device__ __forceinline__ unsigned short f2bf(float f) {   // RNE bf16
  unsigned u = __float_as_uint(f);
  u += 0x7fffu + ((u >> 16) & 1u);
  return (unsigned short)(u >> 16);
}

// xw[d][sl][g][b] = bias[d][g] + sum_k x[t][b][k] * W[d][g][k]   (layer 0, K=256)
__global__ void __launch_bounds__(256) xw_gemm_l0(const float* __restrict__ x,
                                                  const float* __restrict__ W,
                                                  const float* __restrict__ bias,
                                                  float* __restrict__ xwout, int c) {
  const int K = 256;
  __shared__ float Wt[128*68];
  __shared__ float Xt[64*68];
  const int tid = threadIdx.x;
  const int gtile = blockIdx.x, sl = blockIdx.y, d = blockIdx.z;
  const int sg = c*SCH + sl;
  const int t = d ? (511 - sg) : sg;
  const int gq = tid >> 4, bq = tid & 15;
  const int g0 = gtile*128 + gq*8;

  float acc[8][4];
  #pragma unroll
  for (int i = 0; i < 8; ++i) {
    const float bv = bias[d*2048 + g0 + i];
    acc[i][0]=bv; acc[i][1]=bv; acc[i][2]=bv; acc[i][3]=bv;
  }
  const float* Wbase = W + ((size_t)d*2048 + gtile*128)*K;

  for (int kc = 0; kc < K; kc += 64) {
    __syncthreads();
    #pragma unroll
    for (int i = 0; i < 8; ++i) {
      const int f4 = i*256 + tid;
      const int row = f4 >> 4, kk4 = (f4 & 15) << 2;
      *(float4*)(Wt + row*68 + kk4) = *(const float4*)(Wbase + (size_t)row*K + kc + kk4);
    }
    {
      // transpose-stage from x (T,B,256)
      const int bb = tid >> 2, kq = tid & 3;
      const float* src = x + ((size_t)t*64 + bb)*256 + kc + kq*16;
      #pragma unroll
      for (int i = 0; i < 4; ++i) {
        const float4 v = *(const float4*)(src + i*4);
        const int k = kq*16 + i*4;
        Xt[(k+0)*68 + bb] = v.x;
        Xt[(k+1)*68 + bb] = v.y;
        Xt[(k+2)*68 + bb] = v.z;
        Xt[(k+3)*68 + bb] = v.w;
      }
    }
    __syncthreads();
    for (int k4 = 0; k4 < 64; k4 += 4) {
      float4 w[8];
      #pragma unroll
      for (int i = 0; i < 8; ++i) w[i] = *(const float4*)(Wt + (gq*8+i)*68 + k4);
      float4 xv[4];
      #pragma unroll
      for (int kk = 0; kk < 4; ++kk) xv[kk] = *(const float4*)(Xt + (k4+kk)*68 + bq*4);
      #pragma unroll
      for (int i = 0; i < 8; ++i) {
        acc[i][0] += w[i].x*xv[0].x + w[i].y*xv[1].x + w[i].z*xv[2].x + w[i].w*xv[3].x;
        acc[i][1] += w[i].x*xv[0].y + w[i].y*xv[1].y + w[i].z*xv[2].y + w[i].w*xv[3].y;
        acc[i][2] += w[i].x*xv[0].z + w[i].y*xv[1].z + w[i].z*xv[2].z + w[i].w*xv[3].z;
        acc[i][3] += w[i].x*xv[0].w + w[i].y*xv[1].w + w[i].z*xv[2].w + w[i].w*xv[3].w;
      }
    }
  }
  float* op = xwout + (((size_t)d*SCH + sl)*2048 + g0)*64 + bq*4;
  #pragma unroll
  for (int i = 0; i < 8; ++i)
    *(float4*)(op + (size_t)i*64) = make_float4(acc[i][0],acc[i][1],acc[i][2],acc[i][3]);
}

// layer 1: in = h0 bf16 (T,1024,B), K=1024
__global__ void __launch_bounds__(256) xw_gemm_l1(const unsigned short* __restrict__ h0,
                                                  const float* __restrict__ W,
                                                  const float* __restrict__ bias,
                                                  float* __restrict__ xwout, int c) {
  const int K = 1024;
  __shared__ float Wt[128*68];
  __shared__ float Xt[64*68];
  const int tid = threadIdx.x;
  const int gtile = blockIdx.x, sl = blockIdx.y, d = blockIdx.z;
  const int sg = c*SCH + sl;
  const int t = d ? (511 - sg) : sg;
  const int gq = tid >> 4, bq = tid & 15;
  const int g0 = gtile*128 + gq*8;

  float acc[8][4];
  #pragma unroll
  for (int i = 0; i < 8; ++i) {
    const float bv = bias[d*2048 + g0 + i];
    acc[i][0]=bv; acc[i][1]=bv; acc[i][2]=bv; acc[i][3]=bv;
  }
  const float* Wbase = W + ((size_t)d*2048 + gtile*128)*K;
  const unsigned short* Xbase = h0 + (size_t)t*K*64;

  for (int kc = 0; kc < K; kc += 64) {
    __syncthreads();
    #pragma unroll
    for (int i = 0; i < 8; ++i) {
      const int f4 = i*256 + tid;
      const int row = f4 >> 4, kk4 = (f4 & 15) << 2;
      *(float4*)(Wt + row*68 + kk4) = *(const float4*)(Wbase + (size_t)row*K + kc + kk4);
    }
    #pragma unroll
    for (int i = 0; i < 4; ++i) {
      const int idx = i*256 + tid;
      const int k = idx >> 4, b4 = (idx & 15) << 2;
      const uint2 r = *(const uint2*)(Xbase + (size_t)(kc + k)*64 + b4);
      float4 v;
      v.x = __uint_as_float(r.x << 16);
      v.y = __uint_as_float(r.x & 0xffff0000u);
      v.z = __uint_as_float(r.y << 16);
      v.w = __uint_as_float(r.y & 0xffff0000u);
      *(float4*)(Xt + k*68 + b4) = v;
    }
    __syncthreads();
    for (int k4 = 0; k4 < 64; k4 += 4) {
      float4 w[8];
      #pragma unroll
      for (int i = 0; i < 8; ++i) w[i] = *(const float4*)(Wt + (gq*8+i)*68 + k4);
      float4 xv[4];
      #pragma unroll
      for (int kk = 0; kk < 4; ++kk) xv[kk] = *(const float4*)(Xt + (k4+kk)*68 + bq*4);
      #pragma unroll
      for (int i = 0; i < 8; ++i) {
        acc[i][0] += w[i].x*xv[0].x + w[i].y*xv[1].x + w[i].z*xv[2].x + w[i].w*xv[3].x;
        acc[i][1] += w[i].x*xv[0].y + w[i].y*xv[1].y + w[i].z*xv[2].y + w[i].w*xv[3].y;
        acc[i][2] += w[i].x*xv[0].z + w[i].y*xv[1].z + w[i].z*xv[2].z + w[i].w*xv[3].z;
        acc[i][3] += w[i].x*xv[0].w + w[i].y*xv[1].w + w[i].z*xv[2].w + w[i].w*xv[3].w;
      }
    }
  }
  float* op = xwout + (((size_t)d*SCH + sl)*2048 + g0)*64 + bq*4;
  #pragma unroll
  for (int i = 0; i < 8; ++i)
    *(float4*)(op + (size_t)i*64) = make_float4(acc[i][0],acc[i][1],acc[i][2],acc[i][3]);
}

// Recurrent (h @ Whh^T), SCH steps per regular launch, 256 blocks x 256 thr.
// Sync: relaxed flag polls + ONE agent acquire fence per block per step;
// release = ONE agent release fence + relaxed flag store (cooperative-groups
// pattern). K-loop is barrier-free: weights from LDS, h read direct from
// global (L2-shared per XCD after first touch), compiler pipelines loads.
__global__ void __launch_bounds__(256) lstm_recur(
    const float* __restrict__ Whh, const float* __restrict__ xw,
    char* __restrict__ wsb, int layer, int c)
{
  extern __shared__ float lds[];
  float* wlds = lds;          // [16][512] fp32 weights
  float* red  = lds + 8192;   // reduction scratch, 4096 floats

  unsigned short* h0 = (unsigned short*)(wsb + OFF_H0);
  float* outsum  = (float*)(wsb + OFF_OUT);
  float* hbuf    = (float*)(wsb + OFF_HBUF) + (size_t)layer*131072;
  float* cstore  = (float*)(wsb + OFF_CST);
  unsigned* flg  = (unsigned*)(wsb + OFF_FLG);

  const int tid = threadIdx.x;
  const int d     = blockIdx.x >> 7;
  const int slot  = blockIdx.x & 127;
  const int jbase = slot << 2;

  const int kg = tid >> 5;          // 8 k-groups (64 k each across step)
  const int bg = (tid >> 1) & 15;   // 16 batch quads
  const int rg = tid & 1;           // 2 row-groups of 8
  const int lrb = rg << 3;
  const int bcol = bg << 2;
  const int b2  = tid & 63;
  const int jj2 = tid >> 6;

  // stage Whh rows (16 x 512 = 32KB)
  for (int lr = 0; lr < 16; ++lr) {
    const int row = (lr >> 2)*512 + jbase + (lr & 3);
    const float* srch = Whh + ((size_t)d*2048 + row)*512;
    float* dstw = wlds + lr*512;
    for (int k = tid*4; k < 512; k += 1024)
      *(float4*)(dstw + k) = *(const float4*)(srch + k);
  }
  float creg = cstore[((size_t)(layer*2 + d)*512 + jbase + jj2)*64 + b2];
  __syncthreads();

  const unsigned fbase = (unsigned)(layer*2 + d) * 512u;

  for (int sl = 0; sl < SCH; ++sl) {
    const int sg = c*SCH + sl;
    const int t_in = d ? (511 - sg) : sg;
    if (sg > 0) {
      if (tid < 128) {   // relaxed polls: no per-poll cache maintenance
        const unsigned* p = &flg[(size_t)(fbase + (unsigned)sg - 1u)*128 + tid];
        while (__hip_atomic_load(p, __ATOMIC_RELAXED, __HIP_MEMORY_SCOPE_AGENT) == 0u)
          __builtin_amdgcn_s_sleep(1);
      }
      __syncthreads();
      if (tid == 0) __builtin_amdgcn_fence(__ATOMIC_ACQUIRE, "agent");  // one L2/L1 inv
      __syncthreads();
    }
    const float* hin = hbuf + ((sg & 1)*2 + d)*32768;

    float acc[8][4];
    #pragma unroll
    for (int i = 0; i < 8; ++i)
      #pragma unroll
      for (int j = 0; j < 4; ++j) acc[i][j] = 0.0f;

    #pragma unroll 2
    for (int ch = 0; ch < 8; ++ch) {
      const int kc = (ch << 6) + (kg << 3);
      const float* xg = hin + (size_t)kc*64 + bcol;
      const float* wr = wlds + lrb*512 + kc;
      float4 xv[8];
      #pragma unroll
      for (int kk = 0; kk < 8; ++kk) xv[kk] = *(const float4*)(xg + kk*64);
      #pragma unroll
      for (int k4 = 0; k4 < 2; ++k4) {
        float4 wv[8];
        #pragma unroll
        for (int i = 0; i < 8; ++i) wv[i] = *(const float4*)(wr + i*512 + k4*4);
        const float4 x0 = xv[k4*4+0], x1 = xv[k4*4+1], x2 = xv[k4*4+2], x3 = xv[k4*4+3];
        #pragma unroll
        for (int i = 0; i < 8; ++i) {
          acc[i][0] += wv[i].x*x0.x + wv[i].y*x1.x + wv[i].z*x2.x + wv[i].w*x3.x;
          acc[i][1] += wv[i].x*x0.y + wv[i].y*x1.y + wv[i].z*x2.y + wv[i].w*x3.y;
          acc[i][2] += wv[i].x*x0.z + wv[i].y*x1.z + wv[i].z*x2.z + wv[i].w*x3.z;
          acc[i][3] += wv[i].x*x0.w + wv[i].y*x1.w + wv[i].z*x2.w + wv[i].w*x3.w;
        }
      }
    }

    // cross-kg tree reduction through red (8 kg -> 1, natural columns)
    #pragma unroll
    for (int half = 4; half >= 1; half >>= 1) {
      __syncthreads();
      if (kg >= half && kg < 2*half) {
        float* dst = red + (kg - half)*1024 + lrb*64 + bcol;
        #pragma unroll
        for (int i = 0; i < 8; ++i)
          *(float4*)(dst + i*64) = make_float4(acc[i][0], acc[i][1], acc[i][2], acc[i][3]);
      }
      __syncthreads();
      if (kg < half) {
        const float* srcp = red + kg*1024 + lrb*64 + bcol;
        #pragma unroll
        for (int i = 0; i < 8; ++i) {
          const float4 v0 = *(const float4*)(srcp + i*64);
          acc[i][0] += v0.x; acc[i][1] += v0.y; acc[i][2] += v0.z; acc[i][3] += v0.w;
        }
      }
    }
    __syncthreads();
    if (kg == 0) {   // tid 0..31 hold full preacts for all 16 rows
      float* dst = red + lrb*64 + bcol;
      #pragma unroll
      for (int i = 0; i < 8; ++i)
        *(float4*)(dst + i*64) = make_float4(acc[i][0], acc[i][1], acc[i][2], acc[i][3]);
    }
    __syncthreads();

    // epilogue: add precomputed xW preacts (bias folded), gates, state
    {
      const float* xwp = xw + (((size_t)d*SCH + sl)*2048)*64;
      const float pi = red[( 0 + jj2)*64 + b2] + xwp[(size_t)(       jbase + jj2)*64 + b2];
      const float pf = red[( 4 + jj2)*64 + b2] + xwp[(size_t)( 512 + jbase + jj2)*64 + b2];
      const float pg = red[( 8 + jj2)*64 + b2] + xwp[(size_t)(1024 + jbase + jj2)*64 + b2];
      const float po = red[(12 + jj2)*64 + b2] + xwp[(size_t)(1536 + jbase + jj2)*64 + b2];
      const float iv = 1.0f/(1.0f + __expf(-pi));
      const float fv = 1.0f/(1.0f + __expf(-pf));
      const float gv = tanhf(pg);
      const float ov = 1.0f/(1.0f + __expf(-po));
      float cc2 = fv*creg + iv*gv;
      cc2 = fminf(fmaxf(cc2, -100.0f), 100.0f);
      creg = cc2;
      const float h = ov*tanhf(cc2);
      hbuf[(((sg & 1) ^ 1)*2 + d)*32768 + (jbase + jj2)*64 + b2] = h;
      if (layer == 0) {
        h0[(size_t)t_in*65536 + (size_t)(d*512 + jbase + jj2)*64 + b2] = f2bf(h);
      } else {
        atomicAdd(&outsum[(size_t)t_in*32768 + (size_t)(jbase + jj2)*64 + b2], h);
      }
    }
    __syncthreads();   // all waves' stores vmcnt-drained (compiler emits waitcnt 0)
    if (tid == 0) {
      __builtin_amdgcn_fence(__ATOMIC_RELEASE, "agent");   // one L2 writeback
      __hip_atomic_store(&flg[(size_t)(fbase + (unsigned)sg)*128 + slot], 1u,
                         __ATOMIC_RELAXED, __HIP_MEMORY_SCOPE_AGENT);
    }
  }
  // persist cell state for next chunk
  cstore[((size_t)(layer*2 + d)*512 + jbase + jj2)*64 + b2] = creg;
}

// ---- attention / output chain ----
__global__ void __launch_bounds__(256) attn_logits(const float* __restrict__ outsum,
                                                   const float* __restrict__ Wa,
                                                   const float* __restrict__ ba,
                                                   float* __restrict__ e) {
  __shared__ float part[4*64];
  const int t = blockIdx.x;
  const int b = threadIdx.x & 63, jq = threadIdx.x >> 6;
  const float* base = outsum + (size_t)t * 512 * 64;
  float acc = 0.0f;
  for (int j = jq*128; j < jq*128 + 128; ++j)
    acc += base[j*64 + b] * Wa[j];
  part[jq*64 + b] = acc;
  __syncthreads();
  if (threadIdx.x < 64) {
    const int bb = threadIdx.x;
    e[bb*512 + t] = part[0*64+bb] + part[1*64+bb] + part[2*64+bb] + part[3*64+bb] + ba[0];
  }
}

__global__ void __launch_bounds__(256) attn_softmax(const float* __restrict__ e,
                                                    float* __restrict__ attn,
                                                    float* __restrict__ aT) {
  __shared__ float red[256];
  const int b = blockIdx.x, tid = threadIdx.x;
  const float v0 = e[b*512 + tid];
  const float v1 = e[b*512 + 256 + tid];
  red[tid] = fmaxf(v0, v1);
  __syncthreads();
  for (int st = 128; st; st >>= 1) { if (tid < st) red[tid] = fmaxf(red[tid], red[tid+st]); __syncthreads(); }
  const float M = red[0];
  __syncthreads();
  const float e0 = __expf(v0 - M), e1 = __expf(v1 - M);
  red[tid] = e0 + e1;
  __syncthreads();
  for (int st = 128; st; st >>= 1) { if (tid < st) red[tid] += red[tid+st]; __syncthreads(); }
  const float inv = 1.0f / red[0];
  const float a0 = e0*inv, a1 = e1*inv;
  attn[b*512 + tid]       = a0;
  attn[b*512 + 256 + tid] = a1;
  aT[tid*64 + b]       = a0;
  aT[(256+tid)*64 + b] = a1;
}

__global__ void __launch_bounds__(256) attn_pool(const float* __restrict__ outsum,
                                                 const float* __restrict__ aT,
                                                 float* __restrict__ pooled) {
  const int tid = threadIdx.x;
  const int b = tid & 63, jj = tid >> 6;
  const int j = blockIdx.x*4 + jj;
  float acc = 0.0f;
  #pragma unroll 4
  for (int t = 0; t < 512; ++t)
    acc += aT[t*64 + b] * outsum[((size_t)t*512 + j)*64 + b];
  pooled[j*64 + b] = acc;
}

__global__ void __launch_bounds__(128) pred_kern(const float* __restrict__ pooled,
                                                 const float* __restrict__ Wo,
                                                 const float* __restrict__ bo,
                                                 float* __restrict__ out) {
  const int b = blockIdx.x, o = threadIdx.x;
  float acc = bo[o];
  const float* wr = Wo + o*512;
  #pragma unroll 4
  for (int j = 0; j < 512; j += 4) {
    const float4 w = *(const float4*)(wr + j);
    acc += w.x*pooled[(j+0)*64 + b] + w.y*pooled[(j+1)*64 + b]
         + w.z*pooled[(j+2)*64 + b] + w.w*pooled[(j+3)*64 + b];
  }
  out[b*128 + o] = acc;
}

extern "C" void kernel_launch(void* const* d_in, const int* in_sizes, int n_in,
                              void* d_out, int out_size, void* d_ws, size_t ws_size,
                              hipStream_t stream) {
  (void)in_sizes; (void)n_in; (void)out_size; (void)ws_size;
  const float* x    = (const float*)d_in[0];
  const float* Wih0 = (const float*)d_in[1];
  const float* Whh0 = (const float*)d_in[2];
  const float* b0   = (const float*)d_in[3];
  const float* Wih1 = (const float*)d_in[4];
  const float* Whh1 = (const float*)d_in[5];
  const float* b1   = (const float*)d_in[6];
  const float* Wa   = (const float*)d_in[7];
  const float* ba   = (const float*)d_in[8];
  const float* Wo   = (const float*)d_in[9];
  const float* bo   = (const float*)d_in[10];
  float* out = (float*)d_out;
  char* wsb  = (char*)d_ws;

  // zero hbuf + cstore + flags (contiguous), and the atomic-accumulated outsum
  hipMemsetAsync(wsb + OFF_HBUF, 0, SZ_HBUF + SZ_CST + SZ_FLG, stream);
  hipMemsetAsync(wsb + OFF_OUT, 0, SZ_OUT, stream);

  float* xwbuf = (float*)(wsb + OFF_XW);

  // layer 0 (regular launches; stream order provides xw->recur dependency)
  for (int c = 0; c < NCH; ++c) {
    xw_gemm_l0<<<dim3(16, SCH, 2), 256, 0, stream>>>(x, Wih0, b0, xwbuf, c);
    lstm_recur<<<dim3(NWG), dim3(256), RECUR_LDS_BYTES, stream>>>(Whh0, xwbuf, wsb, 0, c);
  }
  // layer 1
  for (int c = 0; c < NCH; ++c) {
    xw_gemm_l1<<<dim3(16, SCH, 2), 256, 0, stream>>>((const unsigned short*)(wsb + OFF_H0),
                                                     Wih1, b1, xwbuf, c);
    lstm_recur<<<dim3(NWG), dim3(256), RECUR_LDS_BYTES, stream>>>(Whh1, xwbuf, wsb, 1, c);
  }

  attn_logits <<<512, 256, 0, stream>>>((float*)(wsb + OFF_OUT), Wa, ba, (float*)(wsb + OFF_E));
  attn_softmax<<< 64, 256, 0, stream>>>((float*)(wsb + OFF_E), out + 8192, (float*)(wsb + OFF_AT));
  attn_pool   <<<128, 256, 0, stream>>>((float*)(wsb + OFF_OUT), (float*)(wsb + OFF_AT),
                                        (float*)(wsb + OFF_POOL));
  pred_kern   <<< 64, 128, 0, stream>>>((float*)(wsb + OFF_POOL), Wo, bo, out);
}

// Round 7
// 17738.937 us; speedup vs baseline: 1.8790x; 1.8790x over previous
//
#include <hip/hip_runtime.h>
#include <cstdint>
#include <cstddef>

#define TT 512
#define NWG 256
#define SCH0 64
#define NCH0 8
#define SCH1 32
#define NCH1 16

// ---- Workspace layout (BYTE offsets), total ~165 MiB.
// Layer-0 xw buffer overlays OUT (outsum only live in layer 1+; zeroed between).
#define OFF_H0   0ul
#define SZ_H0    (512ul*1024ul*64ul*2ul)          /* layer0 out, bf16 (T,1024,B) 64MiB */
#define OFF_OUT  (OFF_H0 + SZ_H0)
#define SZ_OUT   (512ul*512ul*64ul*4ul)           /* l1 fwd+bwd sum fp32; ALSO l0 xw (2*64*2048*64*4 = same size) */
#define OFF_XW1  (OFF_OUT + SZ_OUT)
#define SZ_XW1   (2ul*(size_t)SCH1*2048ul*64ul*4ul) /* layer1 xw chunk, 32MiB */
#define OFF_HBUF (OFF_XW1 + SZ_XW1)
#define SZ_HBUF  (2ul*2ul*2ul*512ul*64ul*4ul)     /* [layer][pp][dir][j][b] fp32 */
#define OFF_CST  (OFF_HBUF + SZ_HBUF)
#define SZ_CST   (2ul*2ul*512ul*64ul*4ul)
#define OFF_FLG  (OFF_CST + SZ_CST)
#define SZ_FLG   (2ul*2ul*512ul*128ul*4ul)        /* u32 flags [layer][dir][step][slot] */
#define OFF_E    (OFF_FLG + SZ_FLG)
#define SZ_E     (64ul*512ul*4ul)
#define OFF_AT   (OFF_E + SZ_E)
#define SZ_AT    (512ul*64ul*4ul)
#define OFF_POOL (OFF_AT + SZ_AT)
#define SZ_POOL  (512ul*64ul*4ul)

#define RECUR_LDS_BYTES 49152   /* wlds [512][16] 32KB + red 16KB */

__device__ __forceinline__ unsigned short f2bf(float f) {   // RNE bf16
  unsigned u = __float_as_uint(f);
  u += 0x7fffu + ((u >> 16) & 1u);
  return (unsigned short)(u >> 16);
}

// xw[d][sl][g][b] = bias[d][g] + sum_k x[t][b][k] * W[d][g][k]   (layer 0, K=256)
__global__ void __launch_bounds__(256) xw_gemm_l0(const float* __restrict__ x,
                                                  const float* __restrict__ W,
                                                  const float* __restrict__ bias,
                                                  float* __restrict__ xwout,
                                                  int s0, int sch) {
  const int K = 256;
  __shared__ float Wt[128*68];
  __shared__ float Xt[64*68];
  const int tid = threadIdx.x;
  const int gtile = blockIdx.x, sl = blockIdx.y, d = blockIdx.z;
  const int sg = s0 + sl;
  const int t = d ? (511 - sg) : sg;
  const int gq = tid >> 4, bq = tid & 15;
  const int g0 = gtile*128 + gq*8;

  float acc[8][4];
  #pragma unroll
  for (int i = 0; i < 8; ++i) {
    const float bv = bias[d*2048 + g0 + i];
    acc[i][0]=bv; acc[i][1]=bv; acc[i][2]=bv; acc[i][3]=bv;
  }
  const float* Wbase = W + ((size_t)d*2048 + gtile*128)*K;

  for (int kc = 0; kc < K; kc += 64) {
    __syncthreads();
    #pragma unroll
    for (int i = 0; i < 8; ++i) {
      const int f4 = i*256 + tid;
      const int row = f4 >> 4, kk4 = (f4 & 15) << 2;
      *(float4*)(Wt + row*68 + kk4) = *(const float4*)(Wbase + (size_t)row*K + kc + kk4);
    }
    {
      const int bb = tid >> 2, kq = tid & 3;
      const float* src = x + ((size_t)t*64 + bb)*256 + kc + kq*16;
      #pragma unroll
      for (int i = 0; i < 4; ++i) {
        const float4 v = *(const float4*)(src + i*4);
        const int k = kq*16 + i*4;
        Xt[(k+0)*68 + bb] = v.x;
        Xt[(k+1)*68 + bb] = v.y;
        Xt[(k+2)*68 + bb] = v.z;
        Xt[(k+3)*68 + bb] = v.w;
      }
    }
    __syncthreads();
    for (int k4 = 0; k4 < 64; k4 += 4) {
      float4 w[8];
      #pragma unroll
      for (int i = 0; i < 8; ++i) w[i] = *(const float4*)(Wt + (gq*8+i)*68 + k4);
      float4 xv[4];
      #pragma unroll
      for (int kk = 0; kk < 4; ++kk) xv[kk] = *(const float4*)(Xt + (k4+kk)*68 + bq*4);
      #pragma unroll
      for (int i = 0; i < 8; ++i) {
        acc[i][0] += w[i].x*xv[0].x + w[i].y*xv[1].x + w[i].z*xv[2].x + w[i].w*xv[3].x;
        acc[i][1] += w[i].x*xv[0].y + w[i].y*xv[1].y + w[i].z*xv[2].y + w[i].w*xv[3].y;
        acc[i][2] += w[i].x*xv[0].z + w[i].y*xv[1].z + w[i].z*xv[2].z + w[i].w*xv[3].z;
        acc[i][3] += w[i].x*xv[0].w + w[i].y*xv[1].w + w[i].z*xv[2].w + w[i].w*xv[3].w;
      }
    }
  }
  float* op = xwout + (((size_t)d*sch + sl)*2048 + g0)*64 + bq*4;
  #pragma unroll
  for (int i = 0; i < 8; ++i)
    *(float4*)(op + (size_t)i*64) = make_float4(acc[i][0],acc[i][1],acc[i][2],acc[i][3]);
}

// layer 1: in = h0 bf16 (T,1024,B), K=1024
__global__ void __launch_bounds__(256) xw_gemm_l1(const unsigned short* __restrict__ h0,
                                                  const float* __restrict__ W,
                                                  const float* __restrict__ bias,
                                                  float* __restrict__ xwout,
                                                  int s0, int sch) {
  const int K = 1024;
  __shared__ float Wt[128*68];
  __shared__ float Xt[64*68];
  const int tid = threadIdx.x;
  const int gtile = blockIdx.x, sl = blockIdx.y, d = blockIdx.z;
  const int sg = s0 + sl;
  const int t = d ? (511 - sg) : sg;
  const int gq = tid >> 4, bq = tid & 15;
  const int g0 = gtile*128 + gq*8;

  float acc[8][4];
  #pragma unroll
  for (int i = 0; i < 8; ++i) {
    const float bv = bias[d*2048 + g0 + i];
    acc[i][0]=bv; acc[i][1]=bv; acc[i][2]=bv; acc[i][3]=bv;
  }
  const float* Wbase = W + ((size_t)d*2048 + gtile*128)*K;
  const unsigned short* Xbase = h0 + (size_t)t*K*64;

  for (int kc = 0; kc < K; kc += 64) {
    __syncthreads();
    #pragma unroll
    for (int i = 0; i < 8; ++i) {
      const int f4 = i*256 + tid;
      const int row = f4 >> 4, kk4 = (f4 & 15) << 2;
      *(float4*)(Wt + row*68 + kk4) = *(const float4*)(Wbase + (size_t)row*K + kc + kk4);
    }
    #pragma unroll
    for (int i = 0; i < 4; ++i) {
      const int idx = i*256 + tid;
      const int k = idx >> 4, b4 = (idx & 15) << 2;
      const uint2 r = *(const uint2*)(Xbase + (size_t)(kc + k)*64 + b4);
      float4 v;
      v.x = __uint_as_float(r.x << 16);
      v.y = __uint_as_float(r.x & 0xffff0000u);
      v.z = __uint_as_float(r.y << 16);
      v.w = __uint_as_float(r.y & 0xffff0000u);
      *(float4*)(Xt + k*68 + b4) = v;
    }
    __syncthreads();
    for (int k4 = 0; k4 < 64; k4 += 4) {
      float4 w[8];
      #pragma unroll
      for (int i = 0; i < 8; ++i) w[i] = *(const float4*)(Wt + (gq*8+i)*68 + k4);
      float4 xv[4];
      #pragma unroll
      for (int kk = 0; kk < 4; ++kk) xv[kk] = *(const float4*)(Xt + (k4+kk)*68 + bq*4);
      #pragma unroll
      for (int i = 0; i < 8; ++i) {
        acc[i][0] += w[i].x*xv[0].x + w[i].y*xv[1].x + w[i].z*xv[2].x + w[i].w*xv[3].x;
        acc[i][1] += w[i].x*xv[0].y + w[i].y*xv[1].y + w[i].z*xv[2].y + w[i].w*xv[3].y;
        acc[i][2] += w[i].x*xv[0].z + w[i].y*xv[1].z + w[i].z*xv[2].z + w[i].w*xv[3].z;
        acc[i][3] += w[i].x*xv[0].w + w[i].y*xv[1].w + w[i].z*xv[2].w + w[i].w*xv[3].w;
      }
    }
  }
  float* op = xwout + (((size_t)d*sch + sl)*2048 + g0)*64 + bq*4;
  #pragma unroll
  for (int i = 0; i < 8; ++i)
    *(float4*)(op + (size_t)i*64) = make_float4(acc[i][0],acc[i][1],acc[i][2],acc[i][3]);
}

// Recurrent (h @ Whh^T). ZERO fences: hbuf + flags accessed ONLY via relaxed
// agent-scope atomics (sc-flagged dword ops -> resolve at device coherence
// point, no L2-wide writeback/invalidate). Ordering: __syncthreads drains
// vmcnt before the flag store; consumers' h loads issue after poll exit.
// Thread map: kg=tid>>5 (8 x 64k), bq=tid&31 (32 x 2 batches); acc[16][2].
__global__ void __launch_bounds__(256) lstm_recur(
    const float* __restrict__ Whh, const float* __restrict__ xw,
    char* __restrict__ wsb, int layer, int s0, int sch)
{
  extern __shared__ float lds[];
  float* wlds = lds;          // [512][16] fp32 weights (k-major)
  float* red  = lds + 8192;   // reduction scratch, 4096 floats

  unsigned short* h0 = (unsigned short*)(wsb + OFF_H0);
  float* outsum  = (float*)(wsb + OFF_OUT);
  float* hbuf    = (float*)(wsb + OFF_HBUF) + (size_t)layer*131072;
  float* cstore  = (float*)(wsb + OFF_CST);
  unsigned* flg  = (unsigned*)(wsb + OFF_FLG);

  const int tid = threadIdx.x;
  const int d     = blockIdx.x >> 7;
  const int slot  = blockIdx.x & 127;
  const int jbase = slot << 2;

  const int kg = tid >> 5;
  const int bq = tid & 31;
  const int b0col = bq << 1;
  const int b2  = tid & 63;
  const int jj2 = tid >> 6;

  // stage Whh rows into [k][16] (lr = g*4+jj)
  for (int lr = 0; lr < 16; ++lr) {
    const int row = (lr >> 2)*512 + jbase + (lr & 3);
    const float* srch = Whh + ((size_t)d*2048 + row)*512;
    for (int k = tid; k < 512; k += 256)
      wlds[k*16 + lr] = srch[k];
  }
  float creg = cstore[((size_t)(layer*2 + d)*512 + jbase + jj2)*64 + b2];
  __syncthreads();

  const unsigned fbase = (unsigned)(layer*2 + d) * 512u;

  for (int sl = 0; sl < sch; ++sl) {
    const int sg = s0 + sl;
    const int t_in = d ? (511 - sg) : sg;
    if (sg > 0) {
      if (tid < 128) {   // relaxed atomic polls -> no cache maintenance
        unsigned* p = &flg[(size_t)(fbase + (unsigned)sg - 1u)*128 + tid];
        while (__hip_atomic_load(p, __ATOMIC_RELAXED, __HIP_MEMORY_SCOPE_AGENT) == 0u)
          __builtin_amdgcn_s_sleep(1);
      }
      __syncthreads();
    }
    float* hin = hbuf + ((sg & 1)*2 + d)*32768;

    float acc[16][2];
    #pragma unroll
    for (int i = 0; i < 16; ++i) { acc[i][0] = 0.0f; acc[i][1] = 0.0f; }

    for (int ch = 0; ch < 8; ++ch) {
      const int kb = (kg << 6) + (ch << 3);
      float xh0[8], xh1[8];
      #pragma unroll
      for (int kk = 0; kk < 8; ++kk) {
        float* hp = hin + (size_t)(kb + kk)*64 + b0col;
        xh0[kk] = __hip_atomic_load(hp,     __ATOMIC_RELAXED, __HIP_MEMORY_SCOPE_AGENT);
        xh1[kk] = __hip_atomic_load(hp + 1, __ATOMIC_RELAXED, __HIP_MEMORY_SCOPE_AGENT);
      }
      #pragma unroll
      for (int kk = 0; kk < 8; ++kk) {
        const float* wk = wlds + (size_t)(kb + kk)*16;
        const float4 w0 = *(const float4*)(wk);
        const float4 w1 = *(const float4*)(wk + 4);
        const float4 w2 = *(const float4*)(wk + 8);
        const float4 w3 = *(const float4*)(wk + 12);
        const float a0 = xh0[kk], a1 = xh1[kk];
        acc[ 0][0] += w0.x*a0; acc[ 0][1] += w0.x*a1;
        acc[ 1][0] += w0.y*a0; acc[ 1][1] += w0.y*a1;
        acc[ 2][0] += w0.z*a0; acc[ 2][1] += w0.z*a1;
        acc[ 3][0] += w0.w*a0; acc[ 3][1] += w0.w*a1;
        acc[ 4][0] += w1.x*a0; acc[ 4][1] += w1.x*a1;
        acc[ 5][0] += w1.y*a0; acc[ 5][1] += w1.y*a1;
        acc[ 6][0] += w1.z*a0; acc[ 6][1] += w1.z*a1;
        acc[ 7][0] += w1.w*a0; acc[ 7][1] += w1.w*a1;
        acc[ 8][0] += w2.x*a0; acc[ 8][1] += w2.x*a1;
        acc[ 9][0] += w2.y*a0; acc[ 9][1] += w2.y*a1;
        acc[10][0] += w2.z*a0; acc[10][1] += w2.z*a1;
        acc[11][0] += w2.w*a0; acc[11][1] += w2.w*a1;
        acc[12][0] += w3.x*a0; acc[12][1] += w3.x*a1;
        acc[13][0] += w3.y*a0; acc[13][1] += w3.y*a1;
        acc[14][0] += w3.z*a0; acc[14][1] += w3.z*a1;
        acc[15][0] += w3.w*a0; acc[15][1] += w3.w*a1;
      }
    }

    // cross-kg tree reduction (8 -> 1) through red[blk][lr][64]
    #pragma unroll
    for (int half = 4; half >= 1; half >>= 1) {
      __syncthreads();
      if (kg >= half && kg < 2*half) {
        float* dst = red + (kg - half)*1024 + b0col;
        #pragma unroll
        for (int lr = 0; lr < 16; ++lr)
          *(float2*)(dst + lr*64) = make_float2(acc[lr][0], acc[lr][1]);
      }
      __syncthreads();
      if (kg < half) {
        const float* sp = red + kg*1024 + b0col;
        #pragma unroll
        for (int lr = 0; lr < 16; ++lr) {
          const float2 v = *(const float2*)(sp + lr*64);
          acc[lr][0] += v.x; acc[lr][1] += v.y;
        }
      }
    }
    __syncthreads();
    if (kg == 0) {
      float* dst = red + b0col;
      #pragma unroll
      for (int lr = 0; lr < 16; ++lr)
        *(float2*)(dst + lr*64) = make_float2(acc[lr][0], acc[lr][1]);
    }
    __syncthreads();

    // epilogue: + xW preacts (bias folded), gates, state
    {
      const float* xwp = xw + (((size_t)d*sch + sl)*2048)*64;
      const float pi = red[( 0 + jj2)*64 + b2] + xwp[(size_t)(       jbase + jj2)*64 + b2];
      const float pf = red[( 4 + jj2)*64 + b2] + xwp[(size_t)( 512 + jbase + jj2)*64 + b2];
      const float pg = red[( 8 + jj2)*64 + b2] + xwp[(size_t)(1024 + jbase + jj2)*64 + b2];
      const float po = red[(12 + jj2)*64 + b2] + xwp[(size_t)(1536 + jbase + jj2)*64 + b2];
      const float iv = 1.0f/(1.0f + __expf(-pi));
      const float fv = 1.0f/(1.0f + __expf(-pf));
      const float gv = tanhf(pg);
      const float ov = 1.0f/(1.0f + __expf(-po));
      float cc2 = fv*creg + iv*gv;
      cc2 = fminf(fmaxf(cc2, -100.0f), 100.0f);
      creg = cc2;
      const float h = ov*tanhf(cc2);
      float* hop = hbuf + (((sg & 1) ^ 1)*2 + d)*32768 + (jbase + jj2)*64 + b2;
      __hip_atomic_store(hop, h, __ATOMIC_RELAXED, __HIP_MEMORY_SCOPE_AGENT);
      if (layer == 0) {
        h0[(size_t)t_in*65536 + (size_t)(d*512 + jbase + jj2)*64 + b2] = f2bf(h);
      } else {
        atomicAdd(&outsum[(size_t)t_in*32768 + (size_t)(jbase + jj2)*64 + b2], h);
      }
    }
    __syncthreads();   // drains each wave's vmcnt before barrier -> h stores ACKed
    if (tid == 0)
      __hip_atomic_store(&flg[(size_t)(fbase + (unsigned)sg)*128 + slot], 1u,
                         __ATOMIC_RELAXED, __HIP_MEMORY_SCOPE_AGENT);
  }
  cstore[((size_t)(layer*2 + d)*512 + jbase + jj2)*64 + b2] = creg;
}

// ---- attention / output chain ----
__global__ void __launch_bounds__(256) attn_logits(const float* __restrict__ outsum,
                                                   const float* __restrict__ Wa,
                                                   const float* __restrict__ ba,
                                                   float* __restrict__ e) {
  __shared__ float part[4*64];
  const int t = blockIdx.x;
  const int b = threadIdx.x & 63, jq = threadIdx.x >> 6;
  const float* base = outsum + (size_t)t * 512 * 64;
  float acc = 0.0f;
  for (int j = jq*128; j < jq*128 + 128; ++j)
    acc += base[j*64 + b] * Wa[j];
  part[jq*64 + b] = acc;
  __syncthreads();
  if (threadIdx.x < 64) {
    const int bb = threadIdx.x;
    e[bb*512 + t] = part[0*64+bb] + part[1*64+bb] + part[2*64+bb] + part[3*64+bb] + ba[0];
  }
}

__global__ void __launch_bounds__(256) attn_softmax(const float* __restrict__ e,
                                                    float* __restrict__ attn,
                                                    float* __restrict__ aT) {
  __shared__ float red[256];
  const int b = blockIdx.x, tid = threadIdx.x;
  const float v0 = e[b*512 + tid];
  const float v1 = e[b*512 + 256 + tid];
  red[tid] = fmaxf(v0, v1);
  __syncthreads();
  for (int st = 128; st; st >>= 1) { if (tid < st) red[tid] = fmaxf(red[tid], red[tid+st]); __syncthreads(); }
  const float M = red[0];
  __syncthreads();
  const float e0 = __expf(v0 - M), e1 = __expf(v1 - M);
  red[tid] = e0 + e1;
  __syncthreads();
  for (int st = 128; st; st >>= 1) { if (tid < st) red[tid] += red[tid+st]; __syncthreads(); }
  const float inv = 1.0f / red[0];
  const float a0 = e0*inv, a1 = e1*inv;
  attn[b*512 + tid]       = a0;
  attn[b*512 + 256 + tid] = a1;
  aT[tid*64 + b]       = a0;
  aT[(256+tid)*64 + b] = a1;
}

__global__ void __launch_bounds__(256) attn_pool(const float* __restrict__ outsum,
                                                 const float* __restrict__ aT,
                                                 float* __restrict__ pooled) {
  const int tid = threadIdx.x;
  const int b = tid & 63, jj = tid >> 6;
  const int j = blockIdx.x*4 + jj;
  float acc = 0.0f;
  #pragma unroll 4
  for (int t = 0; t < 512; ++t)
    acc += aT[t*64 + b] * outsum[((size_t)t*512 + j)*64 + b];
  pooled[j*64 + b] = acc;
}

__global__ void __launch_bounds__(128) pred_kern(const float* __restrict__ pooled,
                                                 const float* __restrict__ Wo,
                                                 const float* __restrict__ bo,
                                                 float* __restrict__ out) {
  const int b = blockIdx.x, o = threadIdx.x;
  float acc = bo[o];
  const float* wr = Wo + o*512;
  #pragma unroll 4
  for (int j = 0; j < 512; j += 4) {
    const float4 w = *(const float4*)(wr + j);
    acc += w.x*pooled[(j+0)*64 + b] + w.y*pooled[(j+1)*64 + b]
         + w.z*pooled[(j+2)*64 + b] + w.w*pooled[(j+3)*64 + b];
  }
  out[b*128 + o] = acc;
}

extern "C" void kernel_launch(void* const* d_in, const int* in_sizes, int n_in,
                              void* d_out, int out_size, void* d_ws, size_t ws_size,
                              hipStream_t stream) {
  (void)in_sizes; (void)n_in; (void)out_size; (void)ws_size;
  const float* x    = (const float*)d_in[0];
  const float* Wih0 = (const float*)d_in[1];
  const float* Whh0 = (const float*)d_in[2];
  const float* b0   = (const float*)d_in[3];
  const float* Wih1 = (const float*)d_in[4];
  const float* Whh1 = (const float*)d_in[5];
  const float* b1   = (const float*)d_in[6];
  const float* Wa   = (const float*)d_in[7];
  const float* ba   = (const float*)d_in[8];
  const float* Wo   = (const float*)d_in[9];
  const float* bo   = (const float*)d_in[10];
  float* out = (float*)d_out;
  char* wsb  = (char*)d_ws;

  // zero hbuf + cstore + flags (contiguous)
  hipMemsetAsync(wsb + OFF_HBUF, 0, SZ_HBUF + SZ_CST + SZ_FLG, stream);

  float* xw0 = (float*)(wsb + OFF_OUT);   // layer-0 xw overlays outsum region
  float* xw1 = (float*)(wsb + OFF_XW1);

  // layer 0: SCH0=64 steps per chunk
  for (int c = 0; c < NCH0; ++c) {
    xw_gemm_l0<<<dim3(16, SCH0, 2), 256, 0, stream>>>(x, Wih0, b0, xw0, c*SCH0, SCH0);
    lstm_recur<<<dim3(NWG), dim3(256), RECUR_LDS_BYTES, stream>>>(Whh0, xw0, wsb, 0, c*SCH0, SCH0);
  }

  // outsum becomes live now; zero it (xw0 overlay no longer needed)
  hipMemsetAsync(wsb + OFF_OUT, 0, SZ_OUT, stream);

  // layer 1: SCH1=32 steps per chunk
  for (int c = 0; c < NCH1; ++c) {
    xw_gemm_l1<<<dim3(16, SCH1, 2), 256, 0, stream>>>((const unsigned short*)(wsb + OFF_H0),
                                                      Wih1, b1, xw1, c*SCH1, SCH1);
    lstm_recur<<<dim3(NWG), dim3(256), RECUR_LDS_BYTES, stream>>>(Whh1, xw1, wsb, 1, c*SCH1, SCH1);
  }

  attn_logits <<<512, 256, 0, stream>>>((float*)(wsb + OFF_OUT), Wa, ba, (float*)(wsb + OFF_E));
  attn_softmax<<< 64, 256, 0, stream>>>((float*)(wsb + OFF_E), out + 8192, (float*)(wsb + OFF_AT));
  attn_pool   <<<128, 256, 0, stream>>>((float*)(wsb + OFF_OUT), (float*)(wsb + OFF_AT),
                                        (float*)(wsb + OFF_POOL));
  pred_kern   <<< 64, 128, 0, stream>>>((float*)(wsb + OFF_POOL), Wo, bo, out);
}